// Round 4
// baseline (707.113 us; speedup 1.0000x reference)
//
#include <hip/hip_runtime.h>

#define N_TOK 49152
#define PER_E 155648      // 38 chunks * 4096 bf16 elems per expert
#define CHUNKS 38

// d_out float offsets
#define TRAJ_OFF 0
#define SCORE_OFF 5898240
#define AUX_OFF  5947392
#define PROB_OFF 5947393

// per-wave LDS element offsets (u16 elems)
#define H1_OFF 0          // 32 x 256, stride 512B (16KB)
#define S_OFF  8192       // 32 x 128, stride 256B (8KB): SH1 then H2-half

typedef __attribute__((ext_vector_type(8))) short short8v;
typedef __attribute__((ext_vector_type(4))) float f32x4;
typedef __attribute__((ext_vector_type(4))) unsigned short u16x4;

__device__ __forceinline__ unsigned short f2bf(float f) {
  unsigned int u = __float_as_uint(f);
  u = (u + 0x7FFFu + ((u >> 16) & 1u)) >> 16;
  return (unsigned short)u;
}
__device__ __forceinline__ float bf2f(unsigned short h) {
  return __uint_as_float(((unsigned int)h) << 16);
}
__device__ __forceinline__ float geluf(float v) {
  return 0.5f * v * (1.0f + erff(v * 0.70710678118654752f));
}

// ---------------- weight prep: fp32 -> bf16, phase-ordered fragment chunks ----------------
// per expert: 38 chunks x 4096 elems; chunk = 8 frags of 512; frag elem = i*512 + lane*8 + j
// frag value = W[k][col], k = kk*32 + (lane>>4)*8 + j, col = fc*16 + (lane&15)
// chunk order: S1[0-3] S2[4-5] T1a[6-9] T1b[10-13] T2a[14-21] T3a[22-25] T2b[26-33] T3b[34-37]
__global__ __launch_bounds__(256) void prep_weights(
    const float* __restrict__ tW1, const float* __restrict__ tW2, const float* __restrict__ tW3,
    const float* __restrict__ sW1, const float* __restrict__ sW2,
    unsigned short* __restrict__ blob)
{
  int id = blockIdx.x * 256 + threadIdx.x;
  if (id >= 6 * PER_E) return;
  int e = id / PER_E;
  int r = id - e * PER_E;
  int c = r >> 12;
  int q = r & 4095;
  int i = q >> 9;
  int lane = (q >> 3) & 63;
  int j = q & 7;
  const float* src; int ncols, kk, fc;
  if (c < 4)       { src = sW1 + e * 16384; ncols = 128; kk = c;                    fc = i; }
  else if (c < 6)  { src = sW2 + e * 8192;  ncols = 64;  kk = ((c - 4) << 1) + (i >> 2); fc = i & 3; }
  else if (c < 10) { src = tW1 + e * 32768; ncols = 256; kk = c - 6;                fc = i; }
  else if (c < 14) { src = tW1 + e * 32768; ncols = 256; kk = c - 10;               fc = 8 + i; }
  else if (c < 22) { src = tW2 + e * 65536; ncols = 256; kk = c - 14;               fc = i; }
  else if (c < 26) { src = tW3 + e * 30720; ncols = 120; kk = c - 22;               fc = i; }
  else if (c < 34) { src = tW2 + e * 65536; ncols = 256; kk = c - 26;               fc = 8 + i; }
  else             { src = tW3 + e * 30720; ncols = 120; kk = (c - 34) + 4;         fc = i; }
  int k = (kk << 5) + ((lane >> 4) << 3) + j;
  int col = (fc << 4) + (lane & 15);
  blob[id] = f2bf(col < ncols ? src[k * ncols + col] : 0.0f);
}

// ---------------- fused fp32 router ----------------
__global__ __launch_bounds__(256) void router_kernel(
    const float* __restrict__ x,
    const float* __restrict__ rW1, const float* __restrict__ rb1,
    const float* __restrict__ rW2, const float* __restrict__ rb2,
    const float* __restrict__ rW3, const float* __restrict__ rb3,
    float* __restrict__ probs_out,
    int* __restrict__ pairTok, float* __restrict__ pairW, int* __restrict__ pairIdx,
    int* __restrict__ cnt, float* __restrict__ probsum)
{
  __shared__ float xs[32][128];
  __shared__ float h1[32][256];
  __shared__ float h2[32][132];
  __shared__ float lg[32][8];
  __shared__ float psum[8];
  __shared__ int lcnt[8], gbase[8];

  int tid = threadIdx.x;
  int tok0 = blockIdx.x * 32;

  for (int i = tid; i < 32 * 32; i += 256) {
    int row = i >> 5, c4 = i & 31;
    *(f32x4*)&xs[row][c4 * 4] = *(const f32x4*)(x + (size_t)(tok0 + row) * 128 + c4 * 4);
  }
  if (tid < 8) { psum[tid] = 0.f; lcnt[tid] = 0; }
  __syncthreads();

  {
    int u0 = (tid & 63) * 4;
    int t0 = (tid >> 6) * 8;
    float a[8][4];
    #pragma unroll
    for (int t = 0; t < 8; ++t)
      #pragma unroll
      for (int u = 0; u < 4; ++u) a[t][u] = 0.f;
    for (int db = 0; db < 32; ++db) {
      int d = db * 4;
      f32x4 wv[4];
      #pragma unroll
      for (int dd = 0; dd < 4; ++dd) wv[dd] = *(const f32x4*)(rW1 + (size_t)(d + dd) * 256 + u0);
      #pragma unroll
      for (int tt = 0; tt < 8; ++tt) {
        f32x4 xv = *(const f32x4*)&xs[t0 + tt][d];
        #pragma unroll
        for (int dd = 0; dd < 4; ++dd)
          #pragma unroll
          for (int uu = 0; uu < 4; ++uu) a[tt][uu] += xv[dd] * wv[dd][uu];
      }
    }
    f32x4 bv = *(const f32x4*)(rb1 + u0);
    #pragma unroll
    for (int tt = 0; tt < 8; ++tt) {
      f32x4 o;
      #pragma unroll
      for (int uu = 0; uu < 4; ++uu) o[uu] = geluf(a[tt][uu] + bv[uu]);
      *(f32x4*)&h1[t0 + tt][u0] = o;
    }
  }
  __syncthreads();

  {
    int u0 = (tid & 31) * 4;
    int t0 = (tid >> 5) * 4;
    float a[4][4];
    #pragma unroll
    for (int t = 0; t < 4; ++t)
      #pragma unroll
      for (int u = 0; u < 4; ++u) a[t][u] = 0.f;
    for (int db = 0; db < 64; ++db) {
      int d = db * 4;
      f32x4 wv[4];
      #pragma unroll
      for (int dd = 0; dd < 4; ++dd) wv[dd] = *(const f32x4*)(rW2 + (size_t)(d + dd) * 128 + u0);
      #pragma unroll
      for (int tt = 0; tt < 4; ++tt) {
        f32x4 xv = *(const f32x4*)&h1[t0 + tt][d];
        #pragma unroll
        for (int dd = 0; dd < 4; ++dd)
          #pragma unroll
          for (int uu = 0; uu < 4; ++uu) a[tt][uu] += xv[dd] * wv[dd][uu];
      }
    }
    f32x4 bv = *(const f32x4*)(rb2 + u0);
    #pragma unroll
    for (int tt = 0; tt < 4; ++tt) {
      f32x4 o;
      #pragma unroll
      for (int uu = 0; uu < 4; ++uu) o[uu] = geluf(a[tt][uu] + bv[uu]);
      *(f32x4*)&h2[t0 + tt][u0] = o;
    }
  }
  __syncthreads();

  if (tid < 192) {
    int t = tid / 6, e = tid - t * 6;
    float s = rb3[e];
    for (int d = 0; d < 128; ++d) s += h2[t][d] * rW3[d * 6 + e];
    lg[t][e] = s;
  }
  __syncthreads();

  int i1 = 0, i2 = 0, lp1 = 0, lp2 = 0;
  float w1 = 0.f, w2 = 0.f;
  int myTok = tok0 + tid;
  if (tid < 32) {
    float l0[6];
    #pragma unroll
    for (int e = 0; e < 6; ++e) l0[e] = lg[tid][e];
    float m = l0[0];
    #pragma unroll
    for (int e = 1; e < 6; ++e) m = fmaxf(m, l0[e]);
    float pe[6]; float ssum = 0.f;
    #pragma unroll
    for (int e = 0; e < 6; ++e) { pe[e] = expf(l0[e] - m); ssum += pe[e]; }
    float inv = 1.f / ssum;
    #pragma unroll
    for (int e = 0; e < 6; ++e) {
      float pr = pe[e] * inv;
      probs_out[(size_t)myTok * 6 + e] = pr;
      atomicAdd(&psum[e], pr);
    }
    float v1 = l0[0]; i1 = 0; float v2 = -1e30f; i2 = -1;
    #pragma unroll
    for (int e = 1; e < 6; ++e) {
      float v = l0[e];
      if (v > v1) { v2 = v1; i2 = i1; v1 = v; i1 = e; }
      else if (v > v2) { v2 = v; i2 = e; }
    }
    float e2 = expf(v2 - v1);
    float denom = 1.f / (1.f + e2);
    w1 = denom; w2 = e2 * denom;
    lp1 = atomicAdd(&lcnt[i1], 1);
    lp2 = atomicAdd(&lcnt[i2], 1);
  }
  __syncthreads();
  if (tid < 6) gbase[tid] = atomicAdd(&cnt[tid], lcnt[tid]);
  __syncthreads();
  if (tid < 32) {
    int g1 = gbase[i1] + lp1, g2 = gbase[i2] + lp2;
    pairTok[i1 * N_TOK + g1] = myTok; pairW[i1 * N_TOK + g1] = w1;
    pairTok[i2 * N_TOK + g2] = myTok; pairW[i2 * N_TOK + g2] = w2;
    pairIdx[2 * myTok]     = i1 * N_TOK + g1;
    pairIdx[2 * myTok + 1] = i2 * N_TOK + g2;
  }
  if (tid < 6) atomicAdd(&probsum[tid], psum[tid]);
}

// ---------------- aux loss + csum ----------------
__global__ void aux_kernel(const float* __restrict__ probsum, const int* __restrict__ cnt,
                           int* __restrict__ csum, float* __restrict__ auxout)
{
  if (threadIdx.x == 0 && blockIdx.x == 0) {
    int s = 0;
    for (int e = 0; e < 6; ++e) { csum[e] = s; s += cnt[e]; }
    float ent = 0.f, l2 = 0.f;
    for (int e = 0; e < 6; ++e) {
      float avg = probsum[e] / (float)N_TOK;
      ent -= avg * logf(avg + 1e-8f);
      float d = avg - (1.0f / 6.0f);
      l2 += d * d;
    }
    l2 *= (1.0f / 6.0f);
    auxout[0] = -ent * 0.01f + 0.01f * l2;
  }
}

// ---------------- expert kernel helpers ----------------
struct B8 { short8v b[8]; };

__device__ __forceinline__ void loadB8(B8& d, const unsigned short* __restrict__ eblob, int c, int lane) {
  const unsigned short* p = eblob + c * 4096 + lane * 8;
  #pragma unroll
  for (int i = 0; i < 8; ++i) d.b[i] = *(const short8v*)(p + i * 512);
}

__device__ __forceinline__ void mm8(const B8& B, short8v A0, short8v A1, f32x4* c0, f32x4* c1) {
  #pragma unroll
  for (int i = 0; i < 8; ++i) {
    c0[i] = __builtin_amdgcn_mfma_f32_16x16x32_bf16(A0, B.b[i], c0[i], 0, 0, 0);
    c1[i] = __builtin_amdgcn_mfma_f32_16x16x32_bf16(A1, B.b[i], c1[i], 0, 0, 0);
  }
}

__device__ __forceinline__ short8v read_a(const unsigned short* ldsbase, int strideB, int row, int koffEl) {
  int b = (row * strideB + koffEl * 2) ^ ((row & 7) << 4);
  return *(const short8v*)((const char*)ldsbase + b);
}

// gelu epilogue -> per-wave LDS, 8 col-frags x 2 row-groups.
// bias: pointer pre-offset to this col-fragment base (bias[fc*16+colb]).
// ldsColBase: column offset inside the LDS buffer (0 unless writing upper half of a 256-col buffer).
__device__ __forceinline__ void epi8(const f32x4* c0, const f32x4* c1, const float* __restrict__ bias,
                                     int ldsColBase, unsigned short* dstLds, int strideB, int lane)
{
  int colb = lane & 15, rsub = (lane >> 4) << 2;
  #pragma unroll
  for (int rowg = 0; rowg < 2; ++rowg) {
    const f32x4* cc = rowg ? c1 : c0;
    #pragma unroll
    for (int fc = 0; fc < 8; ++fc) {
      int fcol = fc * 16 + colb;
      int col = ldsColBase + fcol;
      float bv = bias[fcol];
      #pragma unroll
      for (int r = 0; r < 4; ++r) {
        int row = rowg * 16 + rsub + r;
        int b = (row * strideB + col * 2) ^ ((row & 7) << 4);
        *(unsigned short*)((char*)dstLds + b) = f2bf(geluf(cc[fc][r] + bv));
      }
    }
  }
}

#define ZERO8(A0, A1) { _Pragma("unroll") for (int z = 0; z < 8; ++z) { A0[z] = (f32x4){0.f,0.f,0.f,0.f}; A1[z] = (f32x4){0.f,0.f,0.f,0.f}; } }

// ---------------- wave-autonomous expert kernel: 1 wave = 32 token-rows, weights streamed to regs ----------------
template<int OUTMODE>   // 0 = scratch pair partials, 1 = atomicAdd into d_out
__global__ __launch_bounds__(64, 2) void expert_kernel(
    const float* __restrict__ x,
    const unsigned short* __restrict__ blob,
    const float* __restrict__ tb1, const float* __restrict__ tb2, const float* __restrict__ tb3,
    const float* __restrict__ sb1, const float* __restrict__ sb2,
    const float* __restrict__ sW3, const float* __restrict__ sb3,
    const int* __restrict__ pairTok, const float* __restrict__ pairW,
    const int* __restrict__ cnt, const int* __restrict__ csum,
    float* __restrict__ traj_out, float* __restrict__ score_out,
    unsigned short* __restrict__ trajP, float* __restrict__ scoreP)
{
  int e = blockIdx.y;
  int base = blockIdx.x * 32;
  int count = cnt[e];
  if (base >= count) return;

  __shared__ unsigned short lds[12288];   // 24KB: H1 (16KB) + SH1/H2half (8KB)
  __shared__ int   toksLds[32];
  __shared__ float gwsLds[32];

  int lane = threadIdx.x;
  const unsigned short* eblob = blob + (size_t)e * PER_E;
  int slotbase = csum[e] + base;
  int colb = lane & 15;
  int hi8 = (lane >> 4) << 3;
  int rsub = (lane >> 4) << 2;

  if (lane < 32) {
    int idx = e * N_TOK + base + ((base + lane < count) ? lane : 0);
    toksLds[lane] = pairTok[idx];
    gwsLds[lane] = (base + lane < count) ? pairW[idx] : 0.f;
  }

  B8 bb[2];
  loadB8(bb[0], eblob, 0, lane);

  // gather X A-fragments into registers (held through S1 + T1)
  short8v xf[2][4];
  #pragma unroll
  for (int rowg = 0; rowg < 2; ++rowg) {
    int row = rowg * 16 + colb;
    int tok = toksLds[row];
    const float* px = x + (size_t)tok * 128 + hi8;
    #pragma unroll
    for (int kk = 0; kk < 4; ++kk) {
      f32x4 lo = *(const f32x4*)(px + kk * 32);
      f32x4 hi = *(const f32x4*)(px + kk * 32 + 4);
      short8v v;
      #pragma unroll
      for (int j = 0; j < 4; ++j) { v[j] = (short)f2bf(lo[j]); v[4 + j] = (short)f2bf(hi[j]); }
      xf[rowg][kk] = v;
    }
  }

  // ---- S1: X @ sW1 -> SH1 (chunks 0-3) ----
  {
    f32x4 a0[8], a1[8];
    ZERO8(a0, a1);
    #pragma unroll
    for (int t = 0; t < 4; ++t) {
      loadB8(bb[(t + 1) & 1], eblob, t + 1, lane);
      mm8(bb[t & 1], xf[0][t], xf[1][t], a0, a1);
    }
    epi8(a0, a1, sb1 + e * 128, 0, lds + S_OFF, 256, lane);
  }

  // ---- S2: SH1 @ sW2 -> score (chunks 4-5) ----
  {
    f32x4 a0[4], a1[4];
    #pragma unroll
    for (int z = 0; z < 4; ++z) { a0[z] = (f32x4){0.f,0.f,0.f,0.f}; a1[z] = (f32x4){0.f,0.f,0.f,0.f}; }
    #pragma unroll
    for (int t = 0; t < 2; ++t) {
      int c = 4 + t;
      loadB8(bb[(c + 1) & 1], eblob, c + 1, lane);
      short8v sa[2][2];
      #pragma unroll
      for (int rowg = 0; rowg < 2; ++rowg)
        #pragma unroll
        for (int kl = 0; kl < 2; ++kl)
          sa[rowg][kl] = read_a(lds + S_OFF, 256, rowg * 16 + colb, (t * 2 + kl) * 32 + hi8);
      const B8& B = bb[c & 1];
      #pragma unroll
      for (int i = 0; i < 8; ++i) {
        int kl = i >> 2, fc = i & 3;
        a0[fc] = __builtin_amdgcn_mfma_f32_16x16x32_bf16(sa[0][kl], B.b[i], a0[fc], 0, 0, 0);
        a1[fc] = __builtin_amdgcn_mfma_f32_16x16x32_bf16(sa[1][kl], B.b[i], a1[fc], 0, 0, 0);
      }
    }
    float p0[4] = {0.f,0.f,0.f,0.f}, p1[4] = {0.f,0.f,0.f,0.f};
    #pragma unroll
    for (int fc = 0; fc < 4; ++fc) {
      int col = fc * 16 + colb;
      float bv = sb2[e * 64 + col];
      float wv = sW3[e * 64 + col];
      #pragma unroll
      for (int r = 0; r < 4; ++r) {
        p0[r] += geluf(a0[fc][r] + bv) * wv;
        p1[r] += geluf(a1[fc][r] + bv) * wv;
      }
    }
    #pragma unroll
    for (int r = 0; r < 4; ++r) {
      #pragma unroll
      for (int s = 1; s < 16; s <<= 1) {
        p0[r] += __shfl_xor(p0[r], s);
        p1[r] += __shfl_xor(p1[r], s);
      }
    }
    if (colb == 0) {
      #pragma unroll
      for (int rowg = 0; rowg < 2; ++rowg) {
        #pragma unroll
        for (int r = 0; r < 4; ++r) {
          int row = rowg * 16 + rsub + r;
          if (base + row < count) {
            float v = gwsLds[row] * (((rowg ? p1[r] : p0[r])) + sb3[e]);
            if (OUTMODE == 0) scoreP[slotbase + row] = v;
            else atomicAdd(&score_out[toksLds[row]], v);
          }
        }
      }
    }
  }

  // ---- T1a/T1b: X @ tW1 -> H1 (chunks 6-13) ----
  {
    f32x4 a0[8], a1[8];
    ZERO8(a0, a1);
    #pragma unroll
    for (int t = 0; t < 4; ++t) {
      int c = 6 + t;
      loadB8(bb[(c + 1) & 1], eblob, c + 1, lane);
      mm8(bb[c & 1], xf[0][t], xf[1][t], a0, a1);
    }
    epi8(a0, a1, tb1 + e * 256, 0, lds + H1_OFF, 512, lane);
    ZERO8(a0, a1);
    #pragma unroll
    for (int t = 0; t < 4; ++t) {
      int c = 10 + t;
      loadB8(bb[(c + 1) & 1], eblob, c + 1, lane);
      mm8(bb[c & 1], xf[0][t], xf[1][t], a0, a1);
    }
    epi8(a0, a1, tb1 + e * 256 + 128, 128, lds + H1_OFF, 512, lane);
  }

  f32x4 w30[8], w31[8];   // T3 accumulators, persist T3a -> T3b
  ZERO8(w30, w31);

  // ---- T2a: H1 @ tW2[:,0:128] -> H2half (chunks 14-21) ----
  {
    f32x4 a0[8], a1[8];
    ZERO8(a0, a1);
    #pragma unroll
    for (int t = 0; t < 8; ++t) {
      int c = 14 + t;
      loadB8(bb[(c + 1) & 1], eblob, c + 1, lane);
      short8v A0 = read_a(lds + H1_OFF, 512, colb,      t * 32 + hi8);
      short8v A1 = read_a(lds + H1_OFF, 512, 16 + colb, t * 32 + hi8);
      mm8(bb[c & 1], A0, A1, a0, a1);
    }
    epi8(a0, a1, tb2 + e * 256, 0, lds + S_OFF, 256, lane);
  }

  // ---- T3a: H2half @ tW3[0:128,:] (chunks 22-25) ----
  #pragma unroll
  for (int t = 0; t < 4; ++t) {
    int c = 22 + t;
    loadB8(bb[(c + 1) & 1], eblob, c + 1, lane);
    short8v A0 = read_a(lds + S_OFF, 256, colb,      t * 32 + hi8);
    short8v A1 = read_a(lds + S_OFF, 256, 16 + colb, t * 32 + hi8);
    mm8(bb[c & 1], A0, A1, w30, w31);
  }

  // ---- T2b: H1 @ tW2[:,128:256] -> H2half (chunks 26-33); LDS cols 0-127, bias cols 128-255 ----
  {
    f32x4 a0[8], a1[8];
    ZERO8(a0, a1);
    #pragma unroll
    for (int t = 0; t < 8; ++t) {
      int c = 26 + t;
      loadB8(bb[(c + 1) & 1], eblob, c + 1, lane);
      short8v A0 = read_a(lds + H1_OFF, 512, colb,      t * 32 + hi8);
      short8v A1 = read_a(lds + H1_OFF, 512, 16 + colb, t * 32 + hi8);
      mm8(bb[c & 1], A0, A1, a0, a1);
    }
    epi8(a0, a1, tb2 + e * 256 + 128, 0, lds + S_OFF, 256, lane);
  }

  // ---- T3b: H2half @ tW3[128:256,:] (chunks 34-37) ----
  #pragma unroll
  for (int t = 0; t < 4; ++t) {
    int c = 34 + t;
    if (c + 1 < CHUNKS) loadB8(bb[(c + 1) & 1], eblob, c + 1, lane);
    short8v A0 = read_a(lds + S_OFF, 256, colb,      t * 32 + hi8);
    short8v A1 = read_a(lds + S_OFF, 256, 16 + colb, t * 32 + hi8);
    mm8(bb[c & 1], A0, A1, w30, w31);
  }

  // ---- trajectory epilogue ----
  #pragma unroll
  for (int rowg = 0; rowg < 2; ++rowg) {
    const f32x4* ww = rowg ? w31 : w30;
    #pragma unroll
    for (int r = 0; r < 4; ++r) {
      int row = rowg * 16 + rsub + r;
      if (base + row < count) {
        float gw = gwsLds[row];
        if (OUTMODE == 0) {
          unsigned short* dst = trajP + (size_t)(slotbase + row) * 120;
          #pragma unroll
          for (int fc = 0; fc < 8; ++fc) {
            int col = fc * 16 + colb;
            if (col < 120) dst[col] = f2bf(gw * (ww[fc][r] + tb3[e * 120 + col]));
          }
        } else {
          float* dst = traj_out + (size_t)toksLds[row] * 120;
          #pragma unroll
          for (int fc = 0; fc < 8; ++fc) {
            int col = fc * 16 + colb;
            if (col < 120) atomicAdd(&dst[col], gw * (ww[fc][r] + tb3[e * 120 + col]));
          }
        }
      }
    }
  }
}

// ---------------- combine: sum each token's 2 pair partials ----------------
__global__ __launch_bounds__(256) void combine_kernel(
    const int* __restrict__ pairIdx, const int* __restrict__ csum,
    const unsigned short* __restrict__ trajP, const float* __restrict__ scoreP,
    float* __restrict__ traj_out, float* __restrict__ score_out)
{
  int t = blockIdx.x * 256 + threadIdx.x;
  if (t >= N_TOK) return;
  int p0 = pairIdx[2 * t], p1 = pairIdx[2 * t + 1];
  int e0 = p0 / N_TOK, e1 = p1 / N_TOK;
  size_t s0 = (size_t)csum[e0] + (p0 - e0 * N_TOK);
  size_t s1 = (size_t)csum[e1] + (p1 - e1 * N_TOK);
  const unsigned short* r0 = trajP + s0 * 120;
  const unsigned short* r1 = trajP + s1 * 120;
  float* o = traj_out + (size_t)t * 120;
  #pragma unroll 6
  for (int i = 0; i < 30; ++i) {
    u16x4 a = *(const u16x4*)(r0 + i * 4);
    u16x4 b = *(const u16x4*)(r1 + i * 4);
    f32x4 v;
    #pragma unroll
    for (int jj = 0; jj < 4; ++jj) v[jj] = bf2f(a[jj]) + bf2f(b[jj]);
    *(f32x4*)(o + i * 4) = v;
  }
  score_out[t] = scoreP[s0] + scoreP[s1];
}

extern "C" void kernel_launch(void* const* d_in, const int* in_sizes, int n_in,
                              void* d_out, int out_size, void* d_ws, size_t ws_size,
                              hipStream_t stream) {
  (void)in_sizes; (void)n_in; (void)out_size;
  const float* x   = (const float*)d_in[0];
  const float* rW1 = (const float*)d_in[1];
  const float* rb1 = (const float*)d_in[2];
  const float* rW2 = (const float*)d_in[3];
  const float* rb2 = (const float*)d_in[4];
  const float* rW3 = (const float*)d_in[5];
  const float* rb3 = (const float*)d_in[6];
  const float* tW1 = (const float*)d_in[7];
  const float* tb1 = (const float*)d_in[8];
  const float* tW2 = (const float*)d_in[9];
  const float* tb2 = (const float*)d_in[10];
  const float* tW3 = (const float*)d_in[11];
  const float* tb3 = (const float*)d_in[12];
  const float* sW1 = (const float*)d_in[13];
  const float* sb1 = (const float*)d_in[14];
  const float* sW2 = (const float*)d_in[15];
  const float* sb2 = (const float*)d_in[16];
  const float* sW3 = (const float*)d_in[17];
  const float* sb3 = (const float*)d_in[18];
  float* out = (float*)d_out;

  // workspace carve (bytes)
  char* wsb = (char*)d_ws;
  int*   cnt     = (int*)(wsb + 0);
  float* probsum = (float*)(wsb + 32);
  int*   csum    = (int*)(wsb + 64);
  int*   pairTok = (int*)(wsb + 96);
  float* pairW   = (float*)(wsb + 96 + (size_t)6 * N_TOK * 4);
  int*   pairIdx = (int*)(wsb + 96 + (size_t)12 * N_TOK * 4);
  float* scoreP  = (float*)(wsb + 96 + (size_t)14 * N_TOK * 4);
  unsigned short* blob = (unsigned short*)(wsb + 96 + (size_t)16 * N_TOK * 4);
  unsigned short* trajP = (unsigned short*)(wsb + 96 + (size_t)16 * N_TOK * 4 + (size_t)6 * PER_E * 2);
  size_t need = 96 + (size_t)16 * N_TOK * 4 + (size_t)6 * PER_E * 2 + (size_t)2 * N_TOK * 120 * 2;
  bool scratch = ws_size >= need;

  hipMemsetAsync(wsb, 0, 96, stream);
  if (!scratch) hipMemsetAsync(d_out, 0, (size_t)(N_TOK * 121) * 4, stream);

  prep_weights<<<(6 * PER_E) / 256, 256, 0, stream>>>(tW1, tW2, tW3, sW1, sW2, blob);
  router_kernel<<<N_TOK / 32, 256, 0, stream>>>(x, rW1, rb1, rW2, rb2, rW3, rb3,
                                                out + PROB_OFF, pairTok, pairW, pairIdx, cnt, probsum);
  aux_kernel<<<1, 64, 0, stream>>>(probsum, cnt, csum, out + AUX_OFF);
  if (scratch) {
    expert_kernel<0><<<dim3(N_TOK / 32, 6), 64, 0, stream>>>(
        x, blob, tb1, tb2, tb3, sb1, sb2, sW3, sb3, pairTok, pairW, cnt, csum,
        out + TRAJ_OFF, out + SCORE_OFF, trajP, scoreP);
    combine_kernel<<<N_TOK / 256, 256, 0, stream>>>(pairIdx, csum, trajP, scoreP,
                                                    out + TRAJ_OFF, out + SCORE_OFF);
  } else {
    expert_kernel<1><<<dim3(N_TOK / 32, 6), 64, 0, stream>>>(
        x, blob, tb1, tb2, tb3, sb1, sb2, sW3, sb3, pairTok, pairW, cnt, csum,
        out + TRAJ_OFF, out + SCORE_OFF, trajP, scoreP);
  }
}

// Round 5
// 599.474 us; speedup vs baseline: 1.1796x; 1.1796x over previous
//
#include <hip/hip_runtime.h>

#define N_TOK 49152
#define PER_E 155648      // 19 stages * 8192 bf16 elems per expert
#define NSTAGE 19

// d_out float offsets
#define TRAJ_OFF 0
#define SCORE_OFF 5898240
#define AUX_OFF  5947392
#define PROB_OFF 5947393

typedef __attribute__((ext_vector_type(8))) short short8v;
typedef __attribute__((ext_vector_type(4))) float f32x4;
typedef __attribute__((ext_vector_type(16))) float f32x16;
typedef __attribute__((ext_vector_type(4))) unsigned short u16x4;

typedef __attribute__((address_space(3))) unsigned char lds_byte;
typedef __attribute__((address_space(1))) const unsigned char gl_byte;

__device__ __forceinline__ unsigned short f2bf(float f) {
  unsigned int u = __float_as_uint(f);
  u = (u + 0x7FFFu + ((u >> 16) & 1u)) >> 16;
  return (unsigned short)u;
}
__device__ __forceinline__ float bf2f(unsigned short h) {
  return __uint_as_float(((unsigned int)h) << 16);
}
__device__ __forceinline__ float geluf(float v) {
  return 0.5f * v * (1.0f + erff(v * 0.70710678118654752f));
}

// ---------------- weight prep: fp32 -> bf16, A-fragment stages for 32x32x16 ----------------
// blob per expert = 19 stages x 8192 elems (16KB); stage = 16 frags of 512; elem = f*512 + l*8 + j
// A-frag: unit(row) = u*32 + (l&31), k = ks*16 + (l>>5)*8 + j  [linear, X-input layers]
// perm layers (input = previous MFMA output): k = 32*(ks>>1) + 16*(ks&1) + 4*(l>>5) + (j&3) + 8*(j>>2)
// stages: 0-1 sW1 | 2 sW2(perm) | 3-6 tW1 | 7-14 tW2(perm) | 15-18 tW3(perm)
__global__ __launch_bounds__(256) void prep_weights(
    const float* __restrict__ tW1, const float* __restrict__ tW2, const float* __restrict__ tW3,
    const float* __restrict__ sW1, const float* __restrict__ sW2,
    unsigned short* __restrict__ blob)
{
  int id = blockIdx.x * 256 + threadIdx.x;
  if (id >= 6 * PER_E) return;
  int e = id / PER_E;
  int r = id - e * PER_E;
  int g = r >> 13;
  int q = r & 8191;
  int f = q >> 9;
  int l = (q >> 3) & 63;
  int j = q & 7;
  int hi = l >> 5, cc = l & 31;
  const float* src; int N, ks, u; bool perm;
  if (g < 2)       { src = sW1 + e * 16384; N = 128; ks = g * 4 + (f >> 2); u = f & 3; perm = false; }
  else if (g == 2) { src = sW2 + e * 8192;  N = 64;  ks = f >> 1;           u = f & 1; perm = true;  }
  else if (g < 7)  { int t = g - 3; src = tW1 + e * 32768; N = 256;
                     ks = (t & 1) * 4 + (f >> 2); u = (f & 3) + (t >> 1) * 4; perm = false; }
  else if (g < 15) { int t = g - 7; src = tW2 + e * 65536; N = 256;
                     ks = (t & 3) * 4 + (f >> 2); u = (f & 3) + (t >> 2) * 4; perm = true; }
  else             { int t = g - 15; src = tW3 + e * 30720; N = 120;
                     ks = t * 4 + (f >> 2); u = f & 3; perm = true; }
  int k = perm ? (32 * (ks >> 1) + 16 * (ks & 1) + 4 * hi + (j & 3) + 8 * (j >> 2))
               : (ks * 16 + hi * 8 + j);
  int col = u * 32 + cc;
  blob[id] = f2bf(col < N ? src[k * N + col] : 0.0f);
}

// ---------------- fused fp32 router (unchanged, correctness-proven) ----------------
__global__ __launch_bounds__(256) void router_kernel(
    const float* __restrict__ x,
    const float* __restrict__ rW1, const float* __restrict__ rb1,
    const float* __restrict__ rW2, const float* __restrict__ rb2,
    const float* __restrict__ rW3, const float* __restrict__ rb3,
    float* __restrict__ probs_out,
    int* __restrict__ pairTok, float* __restrict__ pairW, int* __restrict__ pairIdx,
    int* __restrict__ cnt, float* __restrict__ probsum)
{
  __shared__ float xs[32][128];
  __shared__ float h1[32][256];
  __shared__ float h2[32][132];
  __shared__ float lg[32][8];
  __shared__ float psum[8];
  __shared__ int lcnt[8], gbase[8];

  int tid = threadIdx.x;
  int tok0 = blockIdx.x * 32;

  for (int i = tid; i < 32 * 32; i += 256) {
    int row = i >> 5, c4 = i & 31;
    *(f32x4*)&xs[row][c4 * 4] = *(const f32x4*)(x + (size_t)(tok0 + row) * 128 + c4 * 4);
  }
  if (tid < 8) { psum[tid] = 0.f; lcnt[tid] = 0; }
  __syncthreads();

  {
    int u0 = (tid & 63) * 4;
    int t0 = (tid >> 6) * 8;
    float a[8][4];
    #pragma unroll
    for (int t = 0; t < 8; ++t)
      #pragma unroll
      for (int u = 0; u < 4; ++u) a[t][u] = 0.f;
    for (int db = 0; db < 32; ++db) {
      int d = db * 4;
      f32x4 wv[4];
      #pragma unroll
      for (int dd = 0; dd < 4; ++dd) wv[dd] = *(const f32x4*)(rW1 + (size_t)(d + dd) * 256 + u0);
      #pragma unroll
      for (int tt = 0; tt < 8; ++tt) {
        f32x4 xv = *(const f32x4*)&xs[t0 + tt][d];
        #pragma unroll
        for (int dd = 0; dd < 4; ++dd)
          #pragma unroll
          for (int uu = 0; uu < 4; ++uu) a[tt][uu] += xv[dd] * wv[dd][uu];
      }
    }
    f32x4 bv = *(const f32x4*)(rb1 + u0);
    #pragma unroll
    for (int tt = 0; tt < 8; ++tt) {
      f32x4 o;
      #pragma unroll
      for (int uu = 0; uu < 4; ++uu) o[uu] = geluf(a[tt][uu] + bv[uu]);
      *(f32x4*)&h1[t0 + tt][u0] = o;
    }
  }
  __syncthreads();

  {
    int u0 = (tid & 31) * 4;
    int t0 = (tid >> 5) * 4;
    float a[4][4];
    #pragma unroll
    for (int t = 0; t < 4; ++t)
      #pragma unroll
      for (int u = 0; u < 4; ++u) a[t][u] = 0.f;
    for (int db = 0; db < 64; ++db) {
      int d = db * 4;
      f32x4 wv[4];
      #pragma unroll
      for (int dd = 0; dd < 4; ++dd) wv[dd] = *(const f32x4*)(rW2 + (size_t)(d + dd) * 128 + u0);
      #pragma unroll
      for (int tt = 0; tt < 4; ++tt) {
        f32x4 xv = *(const f32x4*)&h1[t0 + tt][d];
        #pragma unroll
        for (int dd = 0; dd < 4; ++dd)
          #pragma unroll
          for (int uu = 0; uu < 4; ++uu) a[tt][uu] += xv[dd] * wv[dd][uu];
      }
    }
    f32x4 bv = *(const f32x4*)(rb2 + u0);
    #pragma unroll
    for (int tt = 0; tt < 4; ++tt) {
      f32x4 o;
      #pragma unroll
      for (int uu = 0; uu < 4; ++uu) o[uu] = geluf(a[tt][uu] + bv[uu]);
      *(f32x4*)&h2[t0 + tt][u0] = o;
    }
  }
  __syncthreads();

  if (tid < 192) {
    int t = tid / 6, e = tid - t * 6;
    float s = rb3[e];
    for (int d = 0; d < 128; ++d) s += h2[t][d] * rW3[d * 6 + e];
    lg[t][e] = s;
  }
  __syncthreads();

  int i1 = 0, i2 = 0, lp1 = 0, lp2 = 0;
  float w1 = 0.f, w2 = 0.f;
  int myTok = tok0 + tid;
  if (tid < 32) {
    float l0[6];
    #pragma unroll
    for (int e = 0; e < 6; ++e) l0[e] = lg[tid][e];
    float m = l0[0];
    #pragma unroll
    for (int e = 1; e < 6; ++e) m = fmaxf(m, l0[e]);
    float pe[6]; float ssum = 0.f;
    #pragma unroll
    for (int e = 0; e < 6; ++e) { pe[e] = expf(l0[e] - m); ssum += pe[e]; }
    float inv = 1.f / ssum;
    #pragma unroll
    for (int e = 0; e < 6; ++e) {
      float pr = pe[e] * inv;
      probs_out[(size_t)myTok * 6 + e] = pr;
      atomicAdd(&psum[e], pr);
    }
    float v1 = l0[0]; i1 = 0; float v2 = -1e30f; i2 = -1;
    #pragma unroll
    for (int e = 1; e < 6; ++e) {
      float v = l0[e];
      if (v > v1) { v2 = v1; i2 = i1; v1 = v; i1 = e; }
      else if (v > v2) { v2 = v; i2 = e; }
    }
    float e2 = expf(v2 - v1);
    float denom = 1.f / (1.f + e2);
    w1 = denom; w2 = e2 * denom;
    lp1 = atomicAdd(&lcnt[i1], 1);
    lp2 = atomicAdd(&lcnt[i2], 1);
  }
  __syncthreads();
  if (tid < 6) gbase[tid] = atomicAdd(&cnt[tid], lcnt[tid]);
  __syncthreads();
  if (tid < 32) {
    int g1 = gbase[i1] + lp1, g2 = gbase[i2] + lp2;
    pairTok[i1 * N_TOK + g1] = myTok; pairW[i1 * N_TOK + g1] = w1;
    pairTok[i2 * N_TOK + g2] = myTok; pairW[i2 * N_TOK + g2] = w2;
    pairIdx[2 * myTok]     = i1 * N_TOK + g1;
    pairIdx[2 * myTok + 1] = i2 * N_TOK + g2;
  }
  if (tid < 6) atomicAdd(&probsum[tid], psum[tid]);
}

// ---------------- aux loss + csum ----------------
__global__ void aux_kernel(const float* __restrict__ probsum, const int* __restrict__ cnt,
                           int* __restrict__ csum, float* __restrict__ auxout)
{
  if (threadIdx.x == 0 && blockIdx.x == 0) {
    int s = 0;
    for (int e = 0; e < 6; ++e) { csum[e] = s; s += cnt[e]; }
    float ent = 0.f, l2 = 0.f;
    for (int e = 0; e < 6; ++e) {
      float avg = probsum[e] / (float)N_TOK;
      ent -= avg * logf(avg + 1e-8f);
      float d = avg - (1.0f / 6.0f);
      l2 += d * d;
    }
    l2 *= (1.0f / 6.0f);
    auxout[0] = -ent * 0.01f + 0.01f * l2;
  }
}

// ---------------- expert kernel ----------------
__device__ __forceinline__ f32x16 MM(short8v a, short8v b, f32x16 c) {
  return __builtin_amdgcn_mfma_f32_32x32x16_bf16(a, b, c, 0, 0, 0);
}

// acc (one 32-unit block) + bias -> gelu -> two B-frags for the next layer (perm-absorbed, no cross-lane)
__device__ __forceinline__ void cvt_frags(const f32x16& a, const float* __restrict__ bp,
                                          short8v& f0, short8v& f1) {
  #pragma unroll
  for (int m = 0; m < 8; ++m) {
    f0[m] = (short)f2bf(geluf(a[m] + bp[(m & 3) + 8 * (m >> 2)]));
    int r = 8 + m;
    f1[m] = (short)f2bf(geluf(a[r] + bp[(r & 3) + 8 * (r >> 2)]));
  }
}

#define STAGE(s) do { \
    const unsigned short* gsrc_ = eblob + (s) * 8192 + w * 2048 + lane * 8; \
    unsigned short* ldst_ = &wlds[((s) & 3) * 8192 + w * 2048]; \
    _Pragma("unroll") \
    for (int i_ = 0; i_ < 4; ++i_) \
      __builtin_amdgcn_global_load_lds((gl_byte*)(gsrc_ + i_ * 512), (lds_byte*)(ldst_ + i_ * 512), 16, 0, 0); \
  } while (0)

#define PIPE(s, nw) do { \
    if ((s) + 2 < NSTAGE) STAGE((s) + 2); \
    asm volatile("s_waitcnt vmcnt(" #nw ")" ::: "memory"); \
    __builtin_amdgcn_s_barrier(); \
  } while (0)

#define FRAG(s, f) (*(const short8v*)(&wlds[((s) & 3) * 8192 + (f) * 512 + lane * 8]))

template<int OUTMODE>   // 0 = scratch pair partials, 1 = atomicAdd into d_out
__global__ __launch_bounds__(256, 2) void expert_kernel(
    const float* __restrict__ x,
    const unsigned short* __restrict__ blob,
    const float* __restrict__ tb1, const float* __restrict__ tb2, const float* __restrict__ tb3,
    const float* __restrict__ sb1, const float* __restrict__ sb2,
    const float* __restrict__ sW3, const float* __restrict__ sb3,
    const int* __restrict__ pairTok, const float* __restrict__ pairW,
    const int* __restrict__ cnt, const int* __restrict__ csum,
    float* __restrict__ traj_out, float* __restrict__ score_out,
    unsigned short* __restrict__ trajP, float* __restrict__ scoreP)
{
  int e = blockIdx.y;
  int base = blockIdx.x * 128;
  int count = cnt[e];
  if (base >= count) return;

  __shared__ __align__(16) unsigned short wlds[4 * 8192];   // 64KB, 4-slot ring
  __shared__ int   toksLds[128];
  __shared__ float gwsLds[128];

  int tid = threadIdx.x;
  int lane = tid & 63;
  int w = tid >> 6;            // 4 waves
  int c = lane & 31;           // token column
  int hi = lane >> 5;
  const unsigned short* eblob = blob + (size_t)e * PER_E;
  int slotbase = csum[e] + base;
  int myrow = w * 32 + c;

  if (tid < 128) {
    int idx = e * N_TOK + base + ((base + tid < count) ? tid : 0);
    toksLds[tid] = pairTok[idx];
    gwsLds[tid] = (base + tid < count) ? pairW[idx] : 0.f;
  }
  __syncthreads();

  STAGE(0);
  STAGE(1);

  // gather X -> bf16 B-frags (token col = lane&31, k = ks*16 + hi*8 + j)
  int tok = toksLds[myrow];
  short8v xf[8];
  {
    const float* px = x + (size_t)tok * 128 + hi * 8;
    #pragma unroll
    for (int ks = 0; ks < 8; ++ks) {
      f32x4 lo = *(const f32x4*)(px + ks * 16);
      f32x4 hv = *(const f32x4*)(px + ks * 16 + 4);
      short8v v;
      #pragma unroll
      for (int j = 0; j < 4; ++j) { v[j] = (short)f2bf(lo[j]); v[4 + j] = (short)f2bf(hv[j]); }
      xf[ks] = v;
    }
  }

  short8v sB[8], h1B[16], h2B[16];

  // ---- S1: sW1 @ X (stages 0-1) ----
  {
    f32x16 sacc[4] = {};
    PIPE(0, 4);
    #pragma unroll
    for (int ksl = 0; ksl < 4; ++ksl)
      #pragma unroll
      for (int u = 0; u < 4; ++u)
        sacc[u] = MM(FRAG(0, ksl * 4 + u), xf[ksl], sacc[u]);
    PIPE(1, 8);
    #pragma unroll
    for (int ksl = 0; ksl < 4; ++ksl)
      #pragma unroll
      for (int u = 0; u < 4; ++u)
        sacc[u] = MM(FRAG(1, ksl * 4 + u), xf[4 + ksl], sacc[u]);
    const float* bp = sb1 + e * 128 + 4 * hi;
    #pragma unroll
    for (int u = 0; u < 4; ++u)
      cvt_frags(sacc[u], bp + u * 32, sB[2 * u], sB[2 * u + 1]);
  }

  // ---- S2: sW2 @ SH1 (stage 2) -> score ----
  {
    f32x16 q0 = {}, q1 = {};
    PIPE(2, 8);
    #pragma unroll
    for (int ksl = 0; ksl < 8; ++ksl) {
      q0 = MM(FRAG(2, ksl * 2 + 0), sB[ksl], q0);
      q1 = MM(FRAG(2, ksl * 2 + 1), sB[ksl], q1);
    }
    const float* b2p = sb2 + e * 64 + 4 * hi;
    const float* w3p = sW3 + e * 64 + 4 * hi;
    float p = 0.f;
    #pragma unroll
    for (int r = 0; r < 16; ++r) {
      int o = (r & 3) + 8 * (r >> 2);
      p += geluf(q0[r] + b2p[o]) * w3p[o];
      p += geluf(q1[r] + b2p[32 + o]) * w3p[32 + o];
    }
    p += __shfl_xor(p, 32);
    if (hi == 0 && base + myrow < count) {
      float v = gwsLds[myrow] * (p + sb3[e]);
      if (OUTMODE == 0) scoreP[slotbase + myrow] = v;
      else atomicAdd(&score_out[tok], v);
    }
  }

  // ---- T1: tW1 @ X (stages 3-6) -> H1 frags ----
  {
    const float* bp = tb1 + e * 256 + 4 * hi;
    f32x16 tacc[4] = {};
    PIPE(3, 8);
    #pragma unroll
    for (int ksl = 0; ksl < 4; ++ksl)
      #pragma unroll
      for (int u = 0; u < 4; ++u)
        tacc[u] = MM(FRAG(3, ksl * 4 + u), xf[ksl], tacc[u]);
    PIPE(4, 8);
    #pragma unroll
    for (int ksl = 0; ksl < 4; ++ksl)
      #pragma unroll
      for (int u = 0; u < 4; ++u)
        tacc[u] = MM(FRAG(4, ksl * 4 + u), xf[4 + ksl], tacc[u]);
    #pragma unroll
    for (int u = 0; u < 4; ++u)
      cvt_frags(tacc[u], bp + u * 32, h1B[2 * u], h1B[2 * u + 1]);

    f32x16 tacc2[4] = {};
    PIPE(5, 8);
    #pragma unroll
    for (int ksl = 0; ksl < 4; ++ksl)
      #pragma unroll
      for (int u = 0; u < 4; ++u)
        tacc2[u] = MM(FRAG(5, ksl * 4 + u), xf[ksl], tacc2[u]);
    PIPE(6, 8);
    #pragma unroll
    for (int ksl = 0; ksl < 4; ++ksl)
      #pragma unroll
      for (int u = 0; u < 4; ++u)
        tacc2[u] = MM(FRAG(6, ksl * 4 + u), xf[4 + ksl], tacc2[u]);
    #pragma unroll
    for (int u = 0; u < 4; ++u)
      cvt_frags(tacc2[u], bp + 128 + u * 32, h1B[8 + 2 * u], h1B[9 + 2 * u]);
  }

  // ---- T2: tW2 @ H1 (stages 7-14) -> H2 frags ----
  {
    const float* bp = tb2 + e * 256 + 4 * hi;
    f32x16 uacc[4] = {};
    #pragma unroll
    for (int st = 7; st <= 10; ++st) {
      PIPE(st, 8);
      #pragma unroll
      for (int ksl = 0; ksl < 4; ++ksl)
        #pragma unroll
        for (int u = 0; u < 4; ++u)
          uacc[u] = MM(FRAG(st, ksl * 4 + u), h1B[(st - 7) * 4 + ksl], uacc[u]);
    }
    #pragma unroll
    for (int u = 0; u < 4; ++u)
      cvt_frags(uacc[u], bp + u * 32, h2B[2 * u], h2B[2 * u + 1]);

    f32x16 uacc2[4] = {};
    #pragma unroll
    for (int st = 11; st <= 14; ++st) {
      PIPE(st, 8);
      #pragma unroll
      for (int ksl = 0; ksl < 4; ++ksl)
        #pragma unroll
        for (int u = 0; u < 4; ++u)
          uacc2[u] = MM(FRAG(st, ksl * 4 + u), h1B[(st - 11) * 4 + ksl], uacc2[u]);
    }
    #pragma unroll
    for (int u = 0; u < 4; ++u)
      cvt_frags(uacc2[u], bp + 128 + u * 32, h2B[8 + 2 * u], h2B[9 + 2 * u]);
  }

  // ---- T3: tW3 @ H2 (stages 15-18) ----
  f32x16 wacc[4] = {};
  {
    PIPE(15, 8);
    #pragma unroll
    for (int ksl = 0; ksl < 4; ++ksl)
      #pragma unroll
      for (int u = 0; u < 4; ++u)
        wacc[u] = MM(FRAG(15, ksl * 4 + u), h2B[0 + ksl], wacc[u]);
    PIPE(16, 8);
    #pragma unroll
    for (int ksl = 0; ksl < 4; ++ksl)
      #pragma unroll
      for (int u = 0; u < 4; ++u)
        wacc[u] = MM(FRAG(16, ksl * 4 + u), h2B[4 + ksl], wacc[u]);
    PIPE(17, 4);
    #pragma unroll
    for (int ksl = 0; ksl < 4; ++ksl)
      #pragma unroll
      for (int u = 0; u < 4; ++u)
        wacc[u] = MM(FRAG(17, ksl * 4 + u), h2B[8 + ksl], wacc[u]);
    PIPE(18, 0);
    #pragma unroll
    for (int ksl = 0; ksl < 4; ++ksl)
      #pragma unroll
      for (int u = 0; u < 4; ++u)
        wacc[u] = MM(FRAG(18, ksl * 4 + u), h2B[12 + ksl], wacc[u]);
  }

  // ---- trajectory epilogue ----
  {
    bool valid = (base + myrow < count);
    float gw = gwsLds[myrow];
    const float* b3p = tb3 + e * 120;
    if (OUTMODE == 0) {
      unsigned short* dst = trajP + (size_t)(slotbase + myrow) * 120;
      if (valid) {
        #pragma unroll
        for (int u = 0; u < 4; ++u)
          #pragma unroll
          for (int m = 0; m < 8; ++m) {
            int r = 2 * m;
            int unit = u * 32 + (r & 3) + 8 * (r >> 2) + 4 * hi;
            if (u < 3 || m < 6) {
              float v0 = gw * (wacc[u][r] + b3p[unit]);
              float v1 = gw * (wacc[u][r + 1] + b3p[unit + 1]);
              *(unsigned int*)(dst + unit) = (unsigned)f2bf(v0) | ((unsigned)f2bf(v1) << 16);
            }
          }
      }
    } else {
      if (valid) {
        float* dst = traj_out + (size_t)tok * 120;
        #pragma unroll
        for (int u = 0; u < 4; ++u)
          #pragma unroll
          for (int r = 0; r < 16; ++r) {
            int unit = u * 32 + (r & 3) + 8 * (r >> 2) + 4 * hi;
            if (unit < 120) atomicAdd(&dst[unit], gw * (wacc[u][r] + b3p[unit]));
          }
      }
    }
  }
}

// ---------------- combine: sum each token's 2 pair partials ----------------
__global__ __launch_bounds__(256) void combine_kernel(
    const int* __restrict__ pairIdx, const int* __restrict__ csum,
    const unsigned short* __restrict__ trajP, const float* __restrict__ scoreP,
    float* __restrict__ traj_out, float* __restrict__ score_out)
{
  int t = blockIdx.x * 256 + threadIdx.x;
  if (t >= N_TOK) return;
  int p0 = pairIdx[2 * t], p1 = pairIdx[2 * t + 1];
  int e0 = p0 / N_TOK, e1 = p1 / N_TOK;
  size_t s0 = (size_t)csum[e0] + (p0 - e0 * N_TOK);
  size_t s1 = (size_t)csum[e1] + (p1 - e1 * N_TOK);
  const unsigned short* r0 = trajP + s0 * 120;
  const unsigned short* r1 = trajP + s1 * 120;
  float* o = traj_out + (size_t)t * 120;
  #pragma unroll 6
  for (int i = 0; i < 30; ++i) {
    u16x4 a = *(const u16x4*)(r0 + i * 4);
    u16x4 b = *(const u16x4*)(r1 + i * 4);
    f32x4 v;
    #pragma unroll
    for (int jj = 0; jj < 4; ++jj) v[jj] = bf2f(a[jj]) + bf2f(b[jj]);
    *(f32x4*)(o + i * 4) = v;
  }
  score_out[t] = scoreP[s0] + scoreP[s1];
}

extern "C" void kernel_launch(void* const* d_in, const int* in_sizes, int n_in,
                              void* d_out, int out_size, void* d_ws, size_t ws_size,
                              hipStream_t stream) {
  (void)in_sizes; (void)n_in; (void)out_size;
  const float* x   = (const float*)d_in[0];
  const float* rW1 = (const float*)d_in[1];
  const float* rb1 = (const float*)d_in[2];
  const float* rW2 = (const float*)d_in[3];
  const float* rb2 = (const float*)d_in[4];
  const float* rW3 = (const float*)d_in[5];
  const float* rb3 = (const float*)d_in[6];
  const float* tW1 = (const float*)d_in[7];
  const float* tb1 = (const float*)d_in[8];
  const float* tW2 = (const float*)d_in[9];
  const float* tb2 = (const float*)d_in[10];
  const float* tW3 = (const float*)d_in[11];
  const float* tb3 = (const float*)d_in[12];
  const float* sW1 = (const float*)d_in[13];
  const float* sb1 = (const float*)d_in[14];
  const float* sW2 = (const float*)d_in[15];
  const float* sb2 = (const float*)d_in[16];
  const float* sW3 = (const float*)d_in[17];
  const float* sb3 = (const float*)d_in[18];
  float* out = (float*)d_out;

  // workspace carve (bytes)
  char* wsb = (char*)d_ws;
  int*   cnt     = (int*)(wsb + 0);
  float* probsum = (float*)(wsb + 32);
  int*   csum    = (int*)(wsb + 64);
  int*   pairTok = (int*)(wsb + 96);
  float* pairW   = (float*)(wsb + 96 + (size_t)6 * N_TOK * 4);
  int*   pairIdx = (int*)(wsb + 96 + (size_t)12 * N_TOK * 4);
  float* scoreP  = (float*)(wsb + 96 + (size_t)14 * N_TOK * 4);
  unsigned short* blob = (unsigned short*)(wsb + 96 + (size_t)16 * N_TOK * 4);
  unsigned short* trajP = (unsigned short*)(wsb + 96 + (size_t)16 * N_TOK * 4 + (size_t)6 * PER_E * 2);
  size_t need = 96 + (size_t)16 * N_TOK * 4 + (size_t)6 * PER_E * 2 + (size_t)2 * N_TOK * 120 * 2;
  bool scratch = ws_size >= need;

  hipMemsetAsync(wsb, 0, 96, stream);
  if (!scratch) hipMemsetAsync(d_out, 0, (size_t)(N_TOK * 121) * 4, stream);

  prep_weights<<<(6 * PER_E) / 256, 256, 0, stream>>>(tW1, tW2, tW3, sW1, sW2, blob);
  router_kernel<<<N_TOK / 32, 256, 0, stream>>>(x, rW1, rb1, rW2, rb2, rW3, rb3,
                                                out + PROB_OFF, pairTok, pairW, pairIdx, cnt, probsum);
  aux_kernel<<<1, 64, 0, stream>>>(probsum, cnt, csum, out + AUX_OFF);
  if (scratch) {
    expert_kernel<0><<<dim3(N_TOK / 128, 6), 256, 0, stream>>>(
        x, blob, tb1, tb2, tb3, sb1, sb2, sW3, sb3, pairTok, pairW, cnt, csum,
        out + TRAJ_OFF, out + SCORE_OFF, trajP, scoreP);
    combine_kernel<<<N_TOK / 256, 256, 0, stream>>>(pairIdx, csum, trajP, scoreP,
                                                    out + TRAJ_OFF, out + SCORE_OFF);
  } else {
    expert_kernel<1><<<dim3(N_TOK / 128, 6), 256, 0, stream>>>(
        x, blob, tb1, tb2, tb3, sb1, sb2, sW3, sb3, pairTok, pairW, cnt, csum,
        out + TRAJ_OFF, out + SCORE_OFF, trajP, scoreP);
  }
}